// Round 8
// baseline (202.072 us; speedup 1.0000x reference)
//
#include <hip/hip_runtime.h>

#define D     512
#define HW    (D * D)
#define BLOCK 256

typedef float f4 __attribute__((ext_vector_type(4)));   // native vec for NT stores

// ---------------------------------------------------------------------------
// R6 postmortem: R5(8px/thr) and R6(16px/thr) identical at 2.07 TB/s, occ 31%,
// VALU 9% -> dispatch time is set by a straggler class, not the stream. The
// stragglers were the scalar/uncoalesced EDGE blocks. R8 (= R7 + compile fix):
// ONE uniform block shape, fully coalesced float4 over the whole image; the
// rare slow pixels (~2.4K/image of 262K) take an exec-masked gather branch
// inside the wave. Row-strip (rows 0..3, always-slow) is spread across blocks
// by stride-128 row interleaving: block ib owns rows {ib,ib+128,ib+256,ib+384}.
// Output written with nontemporal stores (never re-read; preserve L2 for input).
// ---------------------------------------------------------------------------

// Block-uniform corner sample values (exact f32 replication of reference):
//   S = WF*WF*p(510,510) + WC*WF*p(511,510) + WF*WC*p(510,511) + WC*WC*p(511,511)
__device__ __forceinline__ void corner_vals(const float* __restrict__ base1,
    const float* __restrict__ base2, float S1[3], float S2[3])
{
    const float WF = 1.0f - (510.999f - 510.0f);   // x/y-floor weight
    const float WC = 1.0f - (511.0f - 510.999f);   // x/y-ceil  weight
#pragma unroll
    for (int c = 0; c < 3; ++c) {
        const float* c1 = base1 + (size_t)c * HW;
        const float* c2 = base2 + (size_t)c * HW;
        S1[c] = (WF * WF) * c1[510 + D * 510] + (WC * WF) * c1[510 + D * 511]
              + (WF * WC) * c1[511 + D * 510] + (WC * WC) * c1[511 + D * 511];
        S2[c] = (WF * WF) * c2[510 + D * 510] + (WC * WF) * c2[510 + D * 511]
              + (WF * WC) * c2[511 + D * 510] + (WC * WC) * c2[511 + D * 511];
    }
}

// General path: full reference bilinear with per-lane gathers (ind = y + D*x).
__device__ __forceinline__ void samp_gather(const float* __restrict__ im,
    float rx, float ry, float m, float r3[3], float* oob)
{
    float cxq = fminf(fmaxf(rx, 0.001f), 510.999f);
    float cyq = fminf(fmaxf(ry, 0.001f), 510.999f);
    float dx = rx - cxq, dy = ry - cyq;
    *oob += dx * dx + dy * dy;
    float xff = floorf(cxq), xcf = ceilf(cxq);
    float yff = floorf(cyq), ycf = ceilf(cyq);
    float wxf = 1.0f - (cxq - xff), wxc = 1.0f - (xcf - cxq);
    float wyf = 1.0f - (cyq - yff), wyc = 1.0f - (ycf - cyq);
    float w00 = wxf * wyf, w10 = wxc * wyf, w01 = wxf * wyc, w11 = wxc * wyc;
    int xf = (int)xff, xc = (int)xcf, yf = (int)yff, yc = (int)ycf;
    int i00 = yf + D * xf, i10 = yf + D * xc;
    int i01 = yc + D * xf, i11 = yc + D * xc;
#pragma unroll
    for (int c = 0; c < 3; ++c) {
        const float* __restrict__ ch = im + (size_t)c * HW;
        r3[c] += m * (w00 * ch[i00] + w10 * ch[i10] + w01 * ch[i01] + w11 * ch[i11]);
    }
}

// Exact reference per-pixel: fast math unconditionally, rare masked gather.
__device__ __forceinline__ void px_full(const float* __restrict__ base1,
    const float* __restrict__ base2, const float S1[3], const float S2[3],
    float fi, float fj, float cx, float cy, float m1v, float m2v,
    float* oob, float r[3])
{
    float tot = m1v + m2v;
    float inv = 1.0f / tot;
    float m1n = m1v * inv, m2n = m2v * inv;

    float rx1 = (fi + cx) * 512.0f, ry1 = (fj + cy) * 512.0f;
    float rx2 = (fi - cx) * 512.0f, ry2 = (fj - cy) * 512.0f;

    // exact: (fi - |cx|)*512 == min(rx1, rx2) (f32 sub + pow2 mul are exact)
    bool fast = ((fi - fabsf(cx)) * 512.0f >= 510.999f)
             && ((fj - fabsf(cy)) * 512.0f >= 510.999f);

    if (__builtin_expect(!fast, 0)) {
        r[0] = r[1] = r[2] = 0.0f;
        samp_gather(base1, rx1, ry1, m1n, r, oob);
        samp_gather(base2, rx2, ry2, m2n, r, oob);
    } else {
        float dx1 = rx1 - 510.999f, dy1 = ry1 - 510.999f;
        float dx2 = rx2 - 510.999f, dy2 = ry2 - 510.999f;
        *oob += dx1 * dx1 + dy1 * dy1 + dx2 * dx2 + dy2 * dy2;
        r[0] = m1n * S1[0] + m2n * S2[0];
        r[1] = m1n * S1[1] + m2n * S2[1];
        r[2] = m1n * S1[2] + m2n * S2[2];
    }
}

__device__ __forceinline__ void nt_store4(float* p, float a, float b, float c, float d)
{
    f4 v = {a, b, c, d};
    __builtin_nontemporal_store(v, (f4*)p);
}

// Uniform kernel: 128 blocks/image; block ib owns rows {ib,ib+128,ib+256,ib+384}.
// Thread t: half h = t>>7 (wave-uniform), col = (t&127)*4;
//   chunk c in {0,1} -> row = ib + 128*(2c + h). 8 px/thread, float4 I/O.
__global__ void __launch_bounds__(BLOCK) vm_kernel(
    const float* __restrict__ im1, const float* __restrict__ im2,
    const float* __restrict__ C,   const float* __restrict__ M1,
    const float* __restrict__ M2,  float* __restrict__ out,
    float* __restrict__ partials)
{
    int b = blockIdx.x;
    int t = threadIdx.x;
    int n  = b >> 7;
    int ib = b & 127;

    const float* base1 = im1 + (size_t)n * 3 * HW;
    const float* base2 = im2 + (size_t)n * 3 * HW;
    float S1[3], S2[3];
    corner_vals(base1, base2, S1, S2);

    size_t cb = (size_t)n * 2 * HW, mb = (size_t)n * HW, ob = (size_t)n * 3 * HW;

    int h   = t >> 7;                   // 0/1, wave-uniform
    int col = (t & 127) << 2;
    int row0 = ib + (h << 7);           // chunk 0: k = h
    int row1 = ib + ((2 + h) << 7);     // chunk 1: k = 2 + h
    size_t p0 = ((size_t)row0 << 9) + col;
    size_t p1 = ((size_t)row1 << 9) + col;

    float4 cxa = *(const float4*)(C  + cb + p0);
    float4 cya = *(const float4*)(C  + cb + HW + p0);
    float4 m1a = *(const float4*)(M1 + mb + p0);
    float4 m2a = *(const float4*)(M2 + mb + p0);
    float4 cxb = *(const float4*)(C  + cb + p1);
    float4 cyb = *(const float4*)(C  + cb + HW + p1);
    float4 m1b = *(const float4*)(M1 + mb + p1);
    float4 m2b = *(const float4*)(M2 + mb + p1);

    float oob = 0.0f;

    {   // chunk 0
        float fi = (float)row0, fj = (float)col;
        float ra[3], rbv[3], rc[3], rd[3];
        px_full(base1, base2, S1, S2, fi, fj + 0.0f, cxa.x, cya.x, m1a.x, m2a.x, &oob, ra);
        px_full(base1, base2, S1, S2, fi, fj + 1.0f, cxa.y, cya.y, m1a.y, m2a.y, &oob, rbv);
        px_full(base1, base2, S1, S2, fi, fj + 2.0f, cxa.z, cya.z, m1a.z, m2a.z, &oob, rc);
        px_full(base1, base2, S1, S2, fi, fj + 3.0f, cxa.w, cya.w, m1a.w, m2a.w, &oob, rd);
        nt_store4(out + ob + p0,          ra[0], rbv[0], rc[0], rd[0]);
        nt_store4(out + ob + HW + p0,     ra[1], rbv[1], rc[1], rd[1]);
        nt_store4(out + ob + 2 * HW + p0, ra[2], rbv[2], rc[2], rd[2]);
    }
    {   // chunk 1
        float fi = (float)row1, fj = (float)col;
        float ra[3], rbv[3], rc[3], rd[3];
        px_full(base1, base2, S1, S2, fi, fj + 0.0f, cxb.x, cyb.x, m1b.x, m2b.x, &oob, ra);
        px_full(base1, base2, S1, S2, fi, fj + 1.0f, cxb.y, cyb.y, m1b.y, m2b.y, &oob, rbv);
        px_full(base1, base2, S1, S2, fi, fj + 2.0f, cxb.z, cyb.z, m1b.z, m2b.z, &oob, rc);
        px_full(base1, base2, S1, S2, fi, fj + 3.0f, cxb.w, cyb.w, m1b.w, m2b.w, &oob, rd);
        nt_store4(out + ob + p1,          ra[0], rbv[0], rc[0], rd[0]);
        nt_store4(out + ob + HW + p1,     ra[1], rbv[1], rc[1], rd[1]);
        nt_store4(out + ob + 2 * HW + p1, ra[2], rbv[2], rc[2], rd[2]);
    }

    // ---- per-wave oob partial (no barrier, no LDS) ----
    for (int off = 32; off > 0; off >>= 1)
        oob += __shfl_down(oob, off, 64);
    int lane = t & 63, w = t >> 6;
    if (lane == 0)
        partials[(b << 2) + w] = oob;
}

__global__ void __launch_bounds__(BLOCK) reduce_kernel(
    const float* __restrict__ partials, int nparts,
    float* __restrict__ out_last, double scale)
{
    double s = 0.0;
    for (int i = threadIdx.x; i < nparts; i += BLOCK)
        s += (double)partials[i];
    for (int off = 32; off > 0; off >>= 1)
        s += __shfl_down(s, off, 64);

    __shared__ double sm[BLOCK / 64];
    int lane = threadIdx.x & 63;
    int w    = threadIdx.x >> 6;
    if (lane == 0) sm[w] = s;
    __syncthreads();
    if (threadIdx.x == 0)
        *out_last = (float)((sm[0] + sm[1] + sm[2] + sm[3]) * scale);
}

extern "C" void kernel_launch(void* const* d_in, const int* in_sizes, int n_in,
                              void* d_out, int out_size, void* d_ws, size_t ws_size,
                              hipStream_t stream) {
    const float* im1 = (const float*)d_in[0];
    const float* im2 = (const float*)d_in[1];
    const float* C   = (const float*)d_in[2];
    const float* M1  = (const float*)d_in[3];
    const float* M2  = (const float*)d_in[4];
    float* out = (float*)d_out;
    float* ws  = (float*)d_ws;

    int N = in_sizes[3] / HW;        // M1 is [N,1,H,W]
    int blocks = N * 128;            // uniform: 8 px/thread, 2048 blocks

    vm_kernel<<<blocks, BLOCK, 0, stream>>>(im1, im2, C, M1, M2, out, ws);

    // loss = sum / (N*2*HW) / D^2 * 1e-4  (a and b share the mean count)
    double scale = 1.0 / ((double)N * 2.0 * (double)HW) / (double)HW * 1e-4;
    reduce_kernel<<<1, BLOCK, 0, stream>>>(ws, blocks * 4, out + (out_size - 1), scale);
}

// Round 9
// 191.687 us; speedup vs baseline: 1.0542x; 1.0542x over previous
//
#include <hip/hip_runtime.h>

#define D     512
#define HW    (D * D)
#define BLOCK 256

typedef float f4 __attribute__((ext_vector_type(4)));   // native vec for NT stores

// ---------------------------------------------------------------------------
// Structure = R5 (best measured: role-split, edge blocks first, branch-free
// fast blocks) + ONE delta: fast blocks defer ALL output stores to the end of
// the thread (held in registers) and store nontemporally. Theory: stores share
// vmcnt with loads; R5's load->compute->store per chunk forced a full memory-
// pipeline drain (incl. store acks) every 4 px. Deferred stores mean the
// load/compute loop only waits on loads.
// ---------------------------------------------------------------------------

// Block-uniform corner sample values (exact f32 replication of reference):
//   S = WF*WF*p(510,510) + WC*WF*p(511,510) + WF*WC*p(510,511) + WC*WC*p(511,511)
__device__ __forceinline__ void corner_vals(const float* __restrict__ base1,
    const float* __restrict__ base2, float S1[3], float S2[3])
{
    const float WF = 1.0f - (510.999f - 510.0f);   // x/y-floor weight
    const float WC = 1.0f - (511.0f - 510.999f);   // x/y-ceil  weight
#pragma unroll
    for (int c = 0; c < 3; ++c) {
        const float* c1 = base1 + (size_t)c * HW;
        const float* c2 = base2 + (size_t)c * HW;
        S1[c] = (WF * WF) * c1[510 + D * 510] + (WC * WF) * c1[510 + D * 511]
              + (WF * WC) * c1[511 + D * 510] + (WC * WC) * c1[511 + D * 511];
        S2[c] = (WF * WF) * c2[510 + D * 510] + (WC * WF) * c2[510 + D * 511]
              + (WF * WC) * c2[511 + D * 510] + (WC * WC) * c2[511 + D * 511];
    }
}

// Fast-path per-pixel math (identical expressions to previous passing kernel).
__device__ __forceinline__ void fast_px(float fi, float fj, float cx, float cy,
    float m1, float m2, const float S1[3], const float S2[3],
    float* oob, float r[3])
{
    float tot = m1 + m2;
    float inv = 1.0f / tot;
    float m1n = m1 * inv, m2n = m2 * inv;
    float rx1 = (fi + cx) * 512.0f, ry1 = (fj + cy) * 512.0f;
    float rx2 = (fi - cx) * 512.0f, ry2 = (fj - cy) * 512.0f;
    float dx1 = rx1 - 510.999f, dy1 = ry1 - 510.999f;
    float dx2 = rx2 - 510.999f, dy2 = ry2 - 510.999f;
    *oob += dx1 * dx1 + dy1 * dy1 + dx2 * dx2 + dy2 * dy2;
    r[0] = m1n * S1[0] + m2n * S2[0];
    r[1] = m1n * S1[1] + m2n * S2[1];
    r[2] = m1n * S1[2] + m2n * S2[2];
}

// General path: full reference bilinear with per-lane gathers (ind = y + D*x).
__device__ __forceinline__ void samp_gather(const float* __restrict__ im,
    float rx, float ry, float m, float r3[3], float* oob)
{
    float cxq = fminf(fmaxf(rx, 0.001f), 510.999f);
    float cyq = fminf(fmaxf(ry, 0.001f), 510.999f);
    float dx = rx - cxq, dy = ry - cyq;
    *oob += dx * dx + dy * dy;
    float xff = floorf(cxq), xcf = ceilf(cxq);
    float yff = floorf(cyq), ycf = ceilf(cyq);
    float wxf = 1.0f - (cxq - xff), wxc = 1.0f - (xcf - cxq);
    float wyf = 1.0f - (cyq - yff), wyc = 1.0f - (ycf - cyq);
    float w00 = wxf * wyf, w10 = wxc * wyf, w01 = wxf * wyc, w11 = wxc * wyc;
    int xf = (int)xff, xc = (int)xcf, yf = (int)yff, yc = (int)ycf;
    int i00 = yf + D * xf, i10 = yf + D * xc;
    int i01 = yc + D * xf, i11 = yc + D * xc;
#pragma unroll
    for (int c = 0; c < 3; ++c) {
        const float* __restrict__ ch = im + (size_t)c * HW;
        r3[c] += m * (w00 * ch[i00] + w10 * ch[i10] + w01 * ch[i01] + w11 * ch[i11]);
    }
}

// Full reference per-pixel (round-0 proven body): writes out, adds full oob.
__device__ __forceinline__ void ref_px(const float* __restrict__ base1,
    const float* __restrict__ base2, const float S1[3], const float S2[3],
    int i, int j, float cx, float cy, float m1v, float m2v,
    float* __restrict__ outp, size_t ob_pp, float* oob)
{
    float tot = m1v + m2v;
    float inv = 1.0f / tot;
    float m1n = m1v * inv, m2n = m2v * inv;
    float fi = (float)i, fj = (float)j;

    float rx1 = (fi + cx) * 512.0f, ry1 = (fj + cy) * 512.0f;
    float rx2 = (fi - cx) * 512.0f, ry2 = (fj - cy) * 512.0f;

    // exact: (fi - |cx|)*512 == min(rx1, rx2) (f32 sub + pow2 mul are exact)
    bool fast = ((fi - fabsf(cx)) * 512.0f >= 510.999f)
             && ((fj - fabsf(cy)) * 512.0f >= 510.999f);

    float r3[3];
    if (fast) {
        float dx1 = rx1 - 510.999f, dy1 = ry1 - 510.999f;
        float dx2 = rx2 - 510.999f, dy2 = ry2 - 510.999f;
        *oob += dx1 * dx1 + dy1 * dy1 + dx2 * dx2 + dy2 * dy2;
        r3[0] = m1n * S1[0] + m2n * S2[0];
        r3[1] = m1n * S1[1] + m2n * S2[1];
        r3[2] = m1n * S1[2] + m2n * S2[2];
    } else {
        r3[0] = r3[1] = r3[2] = 0.0f;
        samp_gather(base1, rx1, ry1, m1n, r3, oob);
        samp_gather(base2, rx2, ry2, m2n, r3, oob);
    }
    outp[ob_pp]          = r3[0];
    outp[ob_pp + HW]     = r3[1];
    outp[ob_pp + 2 * HW] = r3[2];
}

__device__ __forceinline__ void nt_store4(float* p, const float r[4])
{
    f4 v = {r[0], r[1], r[2], r[3]};
    __builtin_nontemporal_store(v, (f4*)p);
}

// Grid = N*32 edge blocks (first) + N*126 fast blocks (8 px per thread).
__global__ void __launch_bounds__(BLOCK) main_kernel(
    const float* __restrict__ im1, const float* __restrict__ im2,
    const float* __restrict__ C,   const float* __restrict__ M1,
    const float* __restrict__ M2,  float* __restrict__ out,
    float* __restrict__ partials, int eblocks)
{
    int b = blockIdx.x;
    int t = threadIdx.x;
    float oob = 0.0f;

    if (b < eblocks) {
        // ---------------- edge blocks: strip rows 0..7  U  cols 0..7 -------
        int n  = b >> 5;
        int rb = b & 31;

        const float* base1 = im1 + (size_t)n * 3 * HW;
        const float* base2 = im2 + (size_t)n * 3 * HW;
        float S1[3], S2[3];
        corner_vals(base1, base2, S1, S2);

        int i, j; bool valid;
        if (rb < 16) {                   // region A: rows 0..7, half-row each
            i = rb >> 1;
            j = ((rb & 1) << 8) + t;
            valid = true;
        } else {                         // region B: rows 8..511, cols 0..7
            int q = rb - 16;             // 0..15
            i = 8 + (q << 5) + (t >> 3);
            j = t & 7;
            valid = (i < D);
        }

        if (valid) {
            size_t cb = (size_t)n * 2 * HW, mb = (size_t)n * HW;
            size_t ob = (size_t)n * 3 * HW;
            size_t pp = (size_t)i * D + j;
            ref_px(base1, base2, S1, S2, i, j,
                   C[cb + pp], C[cb + HW + pp], M1[mb + pp], M2[mb + pp],
                   out, ob + pp, &oob);
        }
    } else {
        // ---------------- fast blocks: rows 8..511, col-groups 2..127 ------
        int nb = b - eblocks;
        int n  = nb / 126;               // 126 blocks per image
        int ib = nb - n * 126;

        const float* base1 = im1 + (size_t)n * 3 * HW;
        const float* base2 = im2 + (size_t)n * 3 * HW;
        float S1[3], S2[3];
        corner_vals(base1, base2, S1, S2);

        size_t cb = (size_t)n * 2 * HW, mb = (size_t)n * HW;
        size_t ob = (size_t)n * 3 * HW;

        int g0 = (ib << 9) + t;          // group index over rows 8..511
        int g1 = g0 + 256;
        int row0 = 8 + (g0 >> 7), col0 = (g0 & 127) << 2;
        int row1 = 8 + (g1 >> 7), col1 = (g1 & 127) << 2;
        size_t p0 = ((size_t)row0 << 9) + col0;
        size_t p1 = ((size_t)row1 << 9) + col1;
        bool own = (t & 127) >= 2;       // col-groups 0,1 belong to edge blocks

        float4 cxa = *(const float4*)(C  + cb + p0);
        float4 cya = *(const float4*)(C  + cb + HW + p0);
        float4 m1a = *(const float4*)(M1 + mb + p0);
        float4 m2a = *(const float4*)(M2 + mb + p0);
        float4 cxb = *(const float4*)(C  + cb + p1);
        float4 cyb = *(const float4*)(C  + cb + HW + p1);
        float4 m1b = *(const float4*)(M1 + mb + p1);
        float4 m2b = *(const float4*)(M2 + mb + p1);

        // ---- compute ALL 8 px into registers; NO stores inside the chain ----
        float o0a[4], o1a[4], o2a[4];    // chunk 0 outputs (ch0/ch1/ch2)
        float o0b[4], o1b[4], o2b[4];    // chunk 1 outputs
        {
            float fi = (float)row0, fj = (float)col0;
            float ra[3], rbv[3], rc[3], rd[3];
            fast_px(fi, fj + 0.0f, cxa.x, cya.x, m1a.x, m2a.x, S1, S2, &oob, ra);
            fast_px(fi, fj + 1.0f, cxa.y, cya.y, m1a.y, m2a.y, S1, S2, &oob, rbv);
            fast_px(fi, fj + 2.0f, cxa.z, cya.z, m1a.z, m2a.z, S1, S2, &oob, rc);
            fast_px(fi, fj + 3.0f, cxa.w, cya.w, m1a.w, m2a.w, S1, S2, &oob, rd);
            o0a[0]=ra[0]; o0a[1]=rbv[0]; o0a[2]=rc[0]; o0a[3]=rd[0];
            o1a[0]=ra[1]; o1a[1]=rbv[1]; o1a[2]=rc[1]; o1a[3]=rd[1];
            o2a[0]=ra[2]; o2a[1]=rbv[2]; o2a[2]=rc[2]; o2a[3]=rd[2];
        }
        {
            float fi = (float)row1, fj = (float)col1;
            float ra[3], rbv[3], rc[3], rd[3];
            fast_px(fi, fj + 0.0f, cxb.x, cyb.x, m1b.x, m2b.x, S1, S2, &oob, ra);
            fast_px(fi, fj + 1.0f, cxb.y, cyb.y, m1b.y, m2b.y, S1, S2, &oob, rbv);
            fast_px(fi, fj + 2.0f, cxb.z, cyb.z, m1b.z, m2b.z, S1, S2, &oob, rc);
            fast_px(fi, fj + 3.0f, cxb.w, cyb.w, m1b.w, m2b.w, S1, S2, &oob, rd);
            o0b[0]=ra[0]; o0b[1]=rbv[0]; o0b[2]=rc[0]; o0b[3]=rd[0];
            o1b[0]=ra[1]; o1b[1]=rbv[1]; o1b[2]=rc[1]; o1b[3]=rd[1];
            o2b[0]=ra[2]; o2b[1]=rbv[2]; o2b[2]=rc[2]; o2b[3]=rd[2];
        }

        // ---- all stores at the end (nontemporal; nothing waits on them) ----
        if (own) {
            nt_store4(out + ob + p0,          o0a);
            nt_store4(out + ob + HW + p0,     o1a);
            nt_store4(out + ob + 2 * HW + p0, o2a);
            nt_store4(out + ob + p1,          o0b);
            nt_store4(out + ob + HW + p1,     o1b);
            nt_store4(out + ob + 2 * HW + p1, o2b);
        }
        if (!own) oob = 0.0f;            // those pixels are owned by edge blocks
    }

    // ---- per-wave oob partial (no barrier, no LDS) ----
    for (int off = 32; off > 0; off >>= 1)
        oob += __shfl_down(oob, off, 64);
    int lane = t & 63, w = t >> 6;
    if (lane == 0)
        partials[(b << 2) + w] = oob;
}

__global__ void __launch_bounds__(BLOCK) reduce_kernel(
    const float* __restrict__ partials, int nparts,
    float* __restrict__ out_last, double scale)
{
    double s = 0.0;
    for (int i = threadIdx.x; i < nparts; i += BLOCK)
        s += (double)partials[i];
    for (int off = 32; off > 0; off >>= 1)
        s += __shfl_down(s, off, 64);

    __shared__ double sm[BLOCK / 64];
    int lane = threadIdx.x & 63;
    int w    = threadIdx.x >> 6;
    if (lane == 0) sm[w] = s;
    __syncthreads();
    if (threadIdx.x == 0)
        *out_last = (float)((sm[0] + sm[1] + sm[2] + sm[3]) * scale);
}

extern "C" void kernel_launch(void* const* d_in, const int* in_sizes, int n_in,
                              void* d_out, int out_size, void* d_ws, size_t ws_size,
                              hipStream_t stream) {
    const float* im1 = (const float*)d_in[0];
    const float* im2 = (const float*)d_in[1];
    const float* C   = (const float*)d_in[2];
    const float* M1  = (const float*)d_in[3];
    const float* M2  = (const float*)d_in[4];
    float* out = (float*)d_out;
    float* ws  = (float*)d_ws;

    int N = in_sizes[3] / HW;        // M1 is [N,1,H,W]
    int eblocks = N * 32;            // edge blocks first (overlap with bulk)
    int fblocks = N * 126;           // rows 8..511, 512 groups per block
    int blocks  = eblocks + fblocks;

    main_kernel<<<blocks, BLOCK, 0, stream>>>(im1, im2, C, M1, M2, out, ws, eblocks);

    // loss = sum / (N*2*HW) / D^2 * 1e-4  (a and b share the mean count)
    double scale = 1.0 / ((double)N * 2.0 * (double)HW) / (double)HW * 1e-4;
    reduce_kernel<<<1, BLOCK, 0, stream>>>(ws, blocks * 4, out + (out_size - 1), scale);
}

// Round 10
// 191.266 us; speedup vs baseline: 1.0565x; 1.0022x over previous
//
#include <hip/hip_runtime.h>

#define D     512
#define HW    (D * D)
#define BLOCK 256

typedef float f4 __attribute__((ext_vector_type(4)));   // native vec for asm/NT

// ---------------------------------------------------------------------------
// Structure = R9 (role-split, edge blocks first, branch-free fast blocks,
// deferred NT stores) + ONE delta: fast-block input loads are issued via
// inline-asm global_load_dwordx4 (opaque to the scheduler -> cannot be
// serialized), with counted s_waitcnt vmcnt(4)/vmcnt(0) + sched_barrier(0)
// (rule #18: compiler hoists register-only ops past inline-asm waitcnt).
// Guarantees 8 outstanding 1KB loads per wave -> one exposed latency window.
// ---------------------------------------------------------------------------

#define GLOAD(dst, ptr) \
    asm volatile("global_load_dwordx4 %0, %1, off" : "=v"(dst) : "v"(ptr))

// Block-uniform corner sample values (exact f32 replication of reference):
//   S = WF*WF*p(510,510) + WC*WF*p(511,510) + WF*WC*p(510,511) + WC*WC*p(511,511)
__device__ __forceinline__ void corner_vals(const float* __restrict__ base1,
    const float* __restrict__ base2, float S1[3], float S2[3])
{
    const float WF = 1.0f - (510.999f - 510.0f);   // x/y-floor weight
    const float WC = 1.0f - (511.0f - 510.999f);   // x/y-ceil  weight
#pragma unroll
    for (int c = 0; c < 3; ++c) {
        const float* c1 = base1 + (size_t)c * HW;
        const float* c2 = base2 + (size_t)c * HW;
        S1[c] = (WF * WF) * c1[510 + D * 510] + (WC * WF) * c1[510 + D * 511]
              + (WF * WC) * c1[511 + D * 510] + (WC * WC) * c1[511 + D * 511];
        S2[c] = (WF * WF) * c2[510 + D * 510] + (WC * WF) * c2[510 + D * 511]
              + (WF * WC) * c2[511 + D * 510] + (WC * WC) * c2[511 + D * 511];
    }
}

// Fast-path per-pixel math (identical expressions to previous passing kernel).
__device__ __forceinline__ void fast_px(float fi, float fj, float cx, float cy,
    float m1, float m2, const float S1[3], const float S2[3],
    float* oob, float r[3])
{
    float tot = m1 + m2;
    float inv = 1.0f / tot;
    float m1n = m1 * inv, m2n = m2 * inv;
    float rx1 = (fi + cx) * 512.0f, ry1 = (fj + cy) * 512.0f;
    float rx2 = (fi - cx) * 512.0f, ry2 = (fj - cy) * 512.0f;
    float dx1 = rx1 - 510.999f, dy1 = ry1 - 510.999f;
    float dx2 = rx2 - 510.999f, dy2 = ry2 - 510.999f;
    *oob += dx1 * dx1 + dy1 * dy1 + dx2 * dx2 + dy2 * dy2;
    r[0] = m1n * S1[0] + m2n * S2[0];
    r[1] = m1n * S1[1] + m2n * S2[1];
    r[2] = m1n * S1[2] + m2n * S2[2];
}

// General path: full reference bilinear with per-lane gathers (ind = y + D*x).
__device__ __forceinline__ void samp_gather(const float* __restrict__ im,
    float rx, float ry, float m, float r3[3], float* oob)
{
    float cxq = fminf(fmaxf(rx, 0.001f), 510.999f);
    float cyq = fminf(fmaxf(ry, 0.001f), 510.999f);
    float dx = rx - cxq, dy = ry - cyq;
    *oob += dx * dx + dy * dy;
    float xff = floorf(cxq), xcf = ceilf(cxq);
    float yff = floorf(cyq), ycf = ceilf(cyq);
    float wxf = 1.0f - (cxq - xff), wxc = 1.0f - (xcf - cxq);
    float wyf = 1.0f - (cyq - yff), wyc = 1.0f - (ycf - cyq);
    float w00 = wxf * wyf, w10 = wxc * wyf, w01 = wxf * wyc, w11 = wxc * wyc;
    int xf = (int)xff, xc = (int)xcf, yf = (int)yff, yc = (int)ycf;
    int i00 = yf + D * xf, i10 = yf + D * xc;
    int i01 = yc + D * xf, i11 = yc + D * xc;
#pragma unroll
    for (int c = 0; c < 3; ++c) {
        const float* __restrict__ ch = im + (size_t)c * HW;
        r3[c] += m * (w00 * ch[i00] + w10 * ch[i10] + w01 * ch[i01] + w11 * ch[i11]);
    }
}

// Full reference per-pixel (round-0 proven body): writes out, adds full oob.
__device__ __forceinline__ void ref_px(const float* __restrict__ base1,
    const float* __restrict__ base2, const float S1[3], const float S2[3],
    int i, int j, float cx, float cy, float m1v, float m2v,
    float* __restrict__ outp, size_t ob_pp, float* oob)
{
    float tot = m1v + m2v;
    float inv = 1.0f / tot;
    float m1n = m1v * inv, m2n = m2v * inv;
    float fi = (float)i, fj = (float)j;

    float rx1 = (fi + cx) * 512.0f, ry1 = (fj + cy) * 512.0f;
    float rx2 = (fi - cx) * 512.0f, ry2 = (fj - cy) * 512.0f;

    // exact: (fi - |cx|)*512 == min(rx1, rx2) (f32 sub + pow2 mul are exact)
    bool fast = ((fi - fabsf(cx)) * 512.0f >= 510.999f)
             && ((fj - fabsf(cy)) * 512.0f >= 510.999f);

    float r3[3];
    if (fast) {
        float dx1 = rx1 - 510.999f, dy1 = ry1 - 510.999f;
        float dx2 = rx2 - 510.999f, dy2 = ry2 - 510.999f;
        *oob += dx1 * dx1 + dy1 * dy1 + dx2 * dx2 + dy2 * dy2;
        r3[0] = m1n * S1[0] + m2n * S2[0];
        r3[1] = m1n * S1[1] + m2n * S2[1];
        r3[2] = m1n * S1[2] + m2n * S2[2];
    } else {
        r3[0] = r3[1] = r3[2] = 0.0f;
        samp_gather(base1, rx1, ry1, m1n, r3, oob);
        samp_gather(base2, rx2, ry2, m2n, r3, oob);
    }
    outp[ob_pp]          = r3[0];
    outp[ob_pp + HW]     = r3[1];
    outp[ob_pp + 2 * HW] = r3[2];
}

__device__ __forceinline__ void nt_store4(float* p, const float r[4])
{
    f4 v = {r[0], r[1], r[2], r[3]};
    __builtin_nontemporal_store(v, (f4*)p);
}

// Grid = N*32 edge blocks (first) + N*126 fast blocks (8 px per thread).
__global__ void __launch_bounds__(BLOCK) main_kernel(
    const float* __restrict__ im1, const float* __restrict__ im2,
    const float* __restrict__ C,   const float* __restrict__ M1,
    const float* __restrict__ M2,  float* __restrict__ out,
    float* __restrict__ partials, int eblocks)
{
    int b = blockIdx.x;
    int t = threadIdx.x;
    float oob = 0.0f;

    if (b < eblocks) {
        // ---------------- edge blocks: strip rows 0..7  U  cols 0..7 -------
        int n  = b >> 5;
        int rb = b & 31;

        const float* base1 = im1 + (size_t)n * 3 * HW;
        const float* base2 = im2 + (size_t)n * 3 * HW;
        float S1[3], S2[3];
        corner_vals(base1, base2, S1, S2);

        int i, j; bool valid;
        if (rb < 16) {                   // region A: rows 0..7, half-row each
            i = rb >> 1;
            j = ((rb & 1) << 8) + t;
            valid = true;
        } else {                         // region B: rows 8..511, cols 0..7
            int q = rb - 16;             // 0..15
            i = 8 + (q << 5) + (t >> 3);
            j = t & 7;
            valid = (i < D);
        }

        if (valid) {
            size_t cb = (size_t)n * 2 * HW, mb = (size_t)n * HW;
            size_t ob = (size_t)n * 3 * HW;
            size_t pp = (size_t)i * D + j;
            ref_px(base1, base2, S1, S2, i, j,
                   C[cb + pp], C[cb + HW + pp], M1[mb + pp], M2[mb + pp],
                   out, ob + pp, &oob);
        }
    } else {
        // ---------------- fast blocks: rows 8..511, col-groups 2..127 ------
        int nb = b - eblocks;
        int n  = nb / 126;               // 126 blocks per image
        int ib = nb - n * 126;

        const float* base1 = im1 + (size_t)n * 3 * HW;
        const float* base2 = im2 + (size_t)n * 3 * HW;
        float S1[3], S2[3];
        corner_vals(base1, base2, S1, S2);

        size_t cb = (size_t)n * 2 * HW, mb = (size_t)n * HW;
        size_t ob = (size_t)n * 3 * HW;

        int g0 = (ib << 9) + t;          // group index over rows 8..511
        int g1 = g0 + 256;
        int row0 = 8 + (g0 >> 7), col0 = (g0 & 127) << 2;
        int row1 = 8 + (g1 >> 7), col1 = (g1 & 127) << 2;
        size_t p0 = ((size_t)row0 << 9) + col0;
        size_t p1 = ((size_t)row1 << 9) + col1;
        bool own = (t & 127) >= 2;       // col-groups 0,1 belong to edge blocks

        // ---- issue ALL 8 loads via inline asm (scheduler cannot sink) -----
        // issue order: chunk0 {cx,cy,m1,m2}, then chunk1 {cx,cy,m1,m2}
        f4 cxa, cya, m1a, m2a, cxb, cyb, m1b, m2b;
        GLOAD(cxa, C  + cb + p0);
        GLOAD(cya, C  + cb + HW + p0);
        GLOAD(m1a, M1 + mb + p0);
        GLOAD(m2a, M2 + mb + p0);
        GLOAD(cxb, C  + cb + p1);
        GLOAD(cyb, C  + cb + HW + p1);
        GLOAD(m1b, M1 + mb + p1);
        GLOAD(m2b, M2 + mb + p1);

        float o0a[4], o1a[4], o2a[4];    // chunk 0 outputs (ch0/ch1/ch2)
        float o0b[4], o1b[4], o2b[4];    // chunk 1 outputs

        // ---- chunk 0: wait for first 4 loads only (4 remain in flight) ----
        asm volatile("s_waitcnt vmcnt(4)" ::: "memory");
        __builtin_amdgcn_sched_barrier(0);
        {
            float fi = (float)row0, fj = (float)col0;
            float ra[3], rbv[3], rc[3], rd[3];
            fast_px(fi, fj + 0.0f, cxa.x, cya.x, m1a.x, m2a.x, S1, S2, &oob, ra);
            fast_px(fi, fj + 1.0f, cxa.y, cya.y, m1a.y, m2a.y, S1, S2, &oob, rbv);
            fast_px(fi, fj + 2.0f, cxa.z, cya.z, m1a.z, m2a.z, S1, S2, &oob, rc);
            fast_px(fi, fj + 3.0f, cxa.w, cya.w, m1a.w, m2a.w, S1, S2, &oob, rd);
            o0a[0]=ra[0]; o0a[1]=rbv[0]; o0a[2]=rc[0]; o0a[3]=rd[0];
            o1a[0]=ra[1]; o1a[1]=rbv[1]; o1a[2]=rc[1]; o1a[3]=rd[1];
            o2a[0]=ra[2]; o2a[1]=rbv[2]; o2a[2]=rc[2]; o2a[3]=rd[2];
        }

        // ---- chunk 1: drain remaining loads ----
        asm volatile("s_waitcnt vmcnt(0)" ::: "memory");
        __builtin_amdgcn_sched_barrier(0);
        {
            float fi = (float)row1, fj = (float)col1;
            float ra[3], rbv[3], rc[3], rd[3];
            fast_px(fi, fj + 0.0f, cxb.x, cyb.x, m1b.x, m2b.x, S1, S2, &oob, ra);
            fast_px(fi, fj + 1.0f, cxb.y, cyb.y, m1b.y, m2b.y, S1, S2, &oob, rbv);
            fast_px(fi, fj + 2.0f, cxb.z, cyb.z, m1b.z, m2b.z, S1, S2, &oob, rc);
            fast_px(fi, fj + 3.0f, cxb.w, cyb.w, m1b.w, m2b.w, S1, S2, &oob, rd);
            o0b[0]=ra[0]; o0b[1]=rbv[0]; o0b[2]=rc[0]; o0b[3]=rd[0];
            o1b[0]=ra[1]; o1b[1]=rbv[1]; o1b[2]=rc[1]; o1b[3]=rd[1];
            o2b[0]=ra[2]; o2b[1]=rbv[2]; o2b[2]=rc[2]; o2b[3]=rd[2];
        }

        // ---- all stores at the end (nontemporal; nothing waits on them) ----
        if (own) {
            nt_store4(out + ob + p0,          o0a);
            nt_store4(out + ob + HW + p0,     o1a);
            nt_store4(out + ob + 2 * HW + p0, o2a);
            nt_store4(out + ob + p1,          o0b);
            nt_store4(out + ob + HW + p1,     o1b);
            nt_store4(out + ob + 2 * HW + p1, o2b);
        }
        if (!own) oob = 0.0f;            // those pixels are owned by edge blocks
    }

    // ---- per-wave oob partial (no barrier, no LDS) ----
    for (int off = 32; off > 0; off >>= 1)
        oob += __shfl_down(oob, off, 64);
    int lane = t & 63, w = t >> 6;
    if (lane == 0)
        partials[(b << 2) + w] = oob;
}

__global__ void __launch_bounds__(BLOCK) reduce_kernel(
    const float* __restrict__ partials, int nparts,
    float* __restrict__ out_last, double scale)
{
    double s = 0.0;
    for (int i = threadIdx.x; i < nparts; i += BLOCK)
        s += (double)partials[i];
    for (int off = 32; off > 0; off >>= 1)
        s += __shfl_down(s, off, 64);

    __shared__ double sm[BLOCK / 64];
    int lane = threadIdx.x & 63;
    int w    = threadIdx.x >> 6;
    if (lane == 0) sm[w] = s;
    __syncthreads();
    if (threadIdx.x == 0)
        *out_last = (float)((sm[0] + sm[1] + sm[2] + sm[3]) * scale);
}

extern "C" void kernel_launch(void* const* d_in, const int* in_sizes, int n_in,
                              void* d_out, int out_size, void* d_ws, size_t ws_size,
                              hipStream_t stream) {
    const float* im1 = (const float*)d_in[0];
    const float* im2 = (const float*)d_in[1];
    const float* C   = (const float*)d_in[2];
    const float* M1  = (const float*)d_in[3];
    const float* M2  = (const float*)d_in[4];
    float* out = (float*)d_out;
    float* ws  = (float*)d_ws;

    int N = in_sizes[3] / HW;        // M1 is [N,1,H,W]
    int eblocks = N * 32;            // edge blocks first (overlap with bulk)
    int fblocks = N * 126;           // rows 8..511, 512 groups per block
    int blocks  = eblocks + fblocks;

    main_kernel<<<blocks, BLOCK, 0, stream>>>(im1, im2, C, M1, M2, out, ws, eblocks);

    // loss = sum / (N*2*HW) / D^2 * 1e-4  (a and b share the mean count)
    double scale = 1.0 / ((double)N * 2.0 * (double)HW) / (double)HW * 1e-4;
    reduce_kernel<<<1, BLOCK, 0, stream>>>(ws, blocks * 4, out + (out_size - 1), scale);
}